// Round 1
// baseline (321.510 us; speedup 1.0000x reference)
//
#include <hip/hip_runtime.h>

#define AS_GLOBAL __attribute__((address_space(1)))
#define AS_LDS    __attribute__((address_space(3)))

typedef __bf16 bf16;
typedef __bf16 bf16x8 __attribute__((ext_vector_type(8)));
typedef float  f32x4  __attribute__((ext_vector_type(4)));

__device__ __forceinline__ void gload16(const void* g, void* l) {
  __builtin_amdgcn_global_load_lds((const AS_GLOBAL unsigned int*)g,
                                   (AS_LDS unsigned int*)l, 16, 0, 0);
}

// ---------------- prep kernels ----------------

// fp32 -> bf16, 8 elems/thread
__global__ __launch_bounds__(256) void k_cvt_bf16(const float* __restrict__ x,
                                                  bf16* __restrict__ o, int n8) {
  int i = blockIdx.x * blockDim.x + threadIdx.x;
  if (i >= n8) return;
  const float4* p = (const float4*)(x + (size_t)i * 8);
  float4 a = p[0], b = p[1];
  bf16x8 v;
  v[0] = (bf16)a.x; v[1] = (bf16)a.y; v[2] = (bf16)a.z; v[3] = (bf16)a.w;
  v[4] = (bf16)b.x; v[5] = (bf16)b.y; v[6] = (bf16)b.z; v[7] = (bf16)b.w;
  *(bf16x8*)(o + (size_t)i * 8) = v;
}

// W [K=1024][N=1024] fp32 (in,out) -> WT [N][K] bf16 (row n = column n of W)
__global__ __launch_bounds__(256) void k_wt(const float* __restrict__ W,
                                            bf16* __restrict__ WT) {
  int lin = blockIdx.x * blockDim.x + threadIdx.x;  // 0..131071
  int n  = lin & 1023;
  int kc = lin >> 10;  // 0..127 (8-k chunk)
  bf16x8 v;
#pragma unroll
  for (int j = 0; j < 8; ++j) v[j] = (bf16)W[(size_t)(kc * 8 + j) * 1024 + n];
  *(bf16x8*)&WT[(size_t)n * 1024 + kc * 8] = v;
}

__global__ __launch_bounds__(256) void k_bcat(const float* __restrict__ bq,
                                              const float* __restrict__ bk,
                                              const float* __restrict__ bv,
                                              float* __restrict__ bc) {
  int i = blockIdx.x * blockDim.x + threadIdx.x;
  if (i < 1024) bc[i] = bq[i];
  else if (i < 2048) bc[i] = bk[i - 1024];
  else if (i < 3072) bc[i] = bv[i - 2048];
}

// V region of qkv [4096][3072] -> Vt [b][h][d=64][t=2048] bf16
__global__ __launch_bounds__(256) void k_transpose_v(const bf16* __restrict__ qkv,
                                                     bf16* __restrict__ vt) {
  int blk = blockIdx.x;            // (b*16+h)*64 + tc
  int tc = blk & 63, h = (blk >> 6) & 15, b = blk >> 10;
  int d = threadIdx.x & 63, tq = threadIdx.x >> 6;  // tq 0..3
  int t0 = tc * 32 + tq * 8;
  bf16x8 v;
#pragma unroll
  for (int j = 0; j < 8; ++j)
    v[j] = qkv[(size_t)(b * 2048 + t0 + j) * 3072 + 2048 + h * 64 + d];
  *(bf16x8*)&vt[((size_t)(b * 16 + h) * 64 + d) * 2048 + t0] = v;
}

// ---------------- GEMM: C[M,N] = A[M,K] @ Bt[N,K]^T + bias ----------------
// 128x128 tile, 4 waves (2x2), each wave 64x64 via 4x4 frags of 16x16x32 bf16.
// global_load_lds width-16 staging (m97 structure).
template <typename OutT>
__global__ __launch_bounds__(256) void k_gemm_bt(const bf16* __restrict__ A,
                                                 const bf16* __restrict__ Bt,
                                                 const float* __restrict__ bias,
                                                 OutT* __restrict__ C,
                                                 int K, int N) {
  __shared__ bf16 As[128 * 32];
  __shared__ bf16 Bs[128 * 32];
  const int tid = threadIdx.x;
  const int w = tid >> 6, l = tid & 63, g = l >> 4, c = l & 15;
  const int wr = w >> 1, wc = w & 1;
  const int row0 = blockIdx.x * 128, col0 = blockIdx.y * 128;
  f32x4 acc[4][4] = {};

  for (int k0 = 0; k0 < K; k0 += 32) {
#pragma unroll
    for (int it = 0; it < 2; ++it) {
      int idx = it * 256 + tid;      // 0..511 : 16B chunks of the 8KB tile
      int r = idx >> 2, cc = idx & 3;
      gload16(A  + (size_t)(row0 + r) * K + k0 + cc * 8, &As[idx * 8]);
      gload16(Bt + (size_t)(col0 + r) * K + k0 + cc * 8, &Bs[idx * 8]);
    }
    __syncthreads();   // compiler emits s_waitcnt vmcnt(0) before s_barrier
    bf16x8 af[4], bfr[4];
#pragma unroll
    for (int m = 0; m < 4; ++m)
      af[m] = *(const bf16x8*)&As[(wr * 64 + m * 16 + c) * 32 + g * 8];
#pragma unroll
    for (int n = 0; n < 4; ++n)
      bfr[n] = *(const bf16x8*)&Bs[(wc * 64 + n * 16 + c) * 32 + g * 8];
#pragma unroll
    for (int m = 0; m < 4; ++m)
#pragma unroll
      for (int n = 0; n < 4; ++n)
        acc[m][n] = __builtin_amdgcn_mfma_f32_16x16x32_bf16(af[m], bfr[n],
                                                            acc[m][n], 0, 0, 0);
    __syncthreads();
  }

#pragma unroll
  for (int m = 0; m < 4; ++m) {
    int row = row0 + wr * 64 + m * 16 + g * 4;
#pragma unroll
    for (int n = 0; n < 4; ++n) {
      int col = col0 + wc * 64 + n * 16 + c;
      float bv = bias[col];
#pragma unroll
      for (int r = 0; r < 4; ++r) {
        float v = acc[m][n][r] + bv;
        C[(size_t)(row + r) * N + col] = (OutT)v;
      }
    }
  }
}

// ---------------- flash attention ----------------
// grid: (b, h, qtile of 64). 4 waves x 16 q-rows. K=32 s-chunks.
// mask: valid iff s <= q && !(s % 3 == 1 && s >= 4)
__global__ __launch_bounds__(256) void k_attn(const bf16* __restrict__ qkv,
                                              const bf16* __restrict__ vt,
                                              bf16* __restrict__ att) {
  const int blk = blockIdx.x;                      // (b*16+h)*32 + qt
  const int qt = blk & 31, h = (blk >> 5) & 15, b = blk >> 9;
  const int w = threadIdx.x >> 6, l = threadIdx.x & 63, g = l >> 4, c = l & 15;
  const int q0 = qt * 64 + w * 16;
  __shared__ bf16 Plds[4][16 * 32];  // per-wave P tile [16 q][32 s]

  // Q A-fragments (row = c, k = g*8+j), D=64 -> two frags
  const bf16* qb = qkv + (size_t)(b * 2048 + q0 + c) * 3072 + h * 64 + g * 8;
  bf16x8 qf0 = *(const bf16x8*)qb;
  bf16x8 qf1 = *(const bf16x8*)(qb + 32);

  f32x4 o[4] = {};
  float mrow[4] = {-1e30f, -1e30f, -1e30f, -1e30f};
  float ell[4] = {0.f, 0.f, 0.f, 0.f};

  const bf16* kb = qkv + (size_t)(b * 2048 + c) * 3072 + 1024 + h * 64 + g * 8;
  const bf16* vb = vt + ((size_t)(b * 16 + h) * 64) * 2048;
  const int sEnd = q0 + 16;

  for (int s0 = 0; s0 < sEnd; s0 += 32) {
    // S = Q K^T for two 16-wide s-tiles (B-frag: K rows, contiguous 16B loads)
    f32x4 sl = {}, sh = {};
    const bf16* kl = kb + (size_t)s0 * 3072;
    const bf16* kh = kl + (size_t)16 * 3072;
    sl = __builtin_amdgcn_mfma_f32_16x16x32_bf16(qf0, *(const bf16x8*)kl,        sl, 0, 0, 0);
    sl = __builtin_amdgcn_mfma_f32_16x16x32_bf16(qf1, *(const bf16x8*)(kl + 32), sl, 0, 0, 0);
    sh = __builtin_amdgcn_mfma_f32_16x16x32_bf16(qf0, *(const bf16x8*)kh,        sh, 0, 0, 0);
    sh = __builtin_amdgcn_mfma_f32_16x16x32_bf16(qf1, *(const bf16x8*)(kh + 32), sh, 0, 0, 0);

    // scale + mask (C-layout: row = g*4+r, col = c)
    int s_lo = s0 + c, s_hi = s0 + 16 + c;
    bool col_ml = ((s_lo % 3) == 1) && (s_lo >= 4);
    bool col_mh = ((s_hi % 3) == 1) && (s_hi >= 4);
    float mx[4];
#pragma unroll
    for (int r = 0; r < 4; ++r) {
      int q = q0 + g * 4 + r;
      float a = (!col_ml && s_lo <= q) ? sl[r] * 0.125f : -1e30f;
      float d = (!col_mh && s_hi <= q) ? sh[r] * 0.125f : -1e30f;
      sl[r] = a; sh[r] = d;
      mx[r] = fmaxf(a, d);
    }
    // row-max across the 16-lane column group
#pragma unroll
    for (int r = 0; r < 4; ++r) {
      mx[r] = fmaxf(mx[r], __shfl_xor(mx[r], 1));
      mx[r] = fmaxf(mx[r], __shfl_xor(mx[r], 2));
      mx[r] = fmaxf(mx[r], __shfl_xor(mx[r], 4));
      mx[r] = fmaxf(mx[r], __shfl_xor(mx[r], 8));
    }
    float al[4], rs[4];
#pragma unroll
    for (int r = 0; r < 4; ++r) {
      float mn = fmaxf(mrow[r], mx[r]);
      al[r] = __expf(mrow[r] - mn);
      mrow[r] = mn;
      float pl = __expf(sl[r] - mn);
      float ph = __expf(sh[r] - mn);
      rs[r] = pl + ph;
      Plds[w][(g * 4 + r) * 32 + c]      = (bf16)pl;
      Plds[w][(g * 4 + r) * 32 + 16 + c] = (bf16)ph;
    }
#pragma unroll
    for (int r = 0; r < 4; ++r) {
      rs[r] += __shfl_xor(rs[r], 1);
      rs[r] += __shfl_xor(rs[r], 2);
      rs[r] += __shfl_xor(rs[r], 4);
      rs[r] += __shfl_xor(rs[r], 8);
      ell[r] = ell[r] * al[r] + rs[r];
    }
#pragma unroll
    for (int dc = 0; dc < 4; ++dc)
#pragma unroll
      for (int r = 0; r < 4; ++r) o[dc][r] *= al[r];

    // P LDS round-trip: wait cross-lane writes, then read A-frag
    asm volatile("s_waitcnt lgkmcnt(0)" ::: "memory");
    __builtin_amdgcn_sched_barrier(0);
    bf16x8 pf = *(const bf16x8*)&Plds[w][c * 32 + g * 8];

    // O += P @ V  (B-frag from Vt: contiguous 16B loads along t)
#pragma unroll
    for (int dc = 0; dc < 4; ++dc) {
      bf16x8 vf = *(const bf16x8*)(vb + (size_t)(dc * 16 + c) * 2048 + s0 + g * 8);
      o[dc] = __builtin_amdgcn_mfma_f32_16x16x32_bf16(pf, vf, o[dc], 0, 0, 0);
    }
  }

#pragma unroll
  for (int dc = 0; dc < 4; ++dc)
#pragma unroll
    for (int r = 0; r < 4; ++r) {
      int q = q0 + g * 4 + r;
      att[(size_t)(b * 2048 + q) * 1024 + h * 64 + dc * 16 + c] =
          (bf16)(o[dc][r] / ell[r]);
    }
}

// ---------------- launcher ----------------
extern "C" void kernel_launch(void* const* d_in, const int* in_sizes, int n_in,
                              void* d_out, int out_size, void* d_ws, size_t ws_size,
                              hipStream_t stream) {
  const float* x  = (const float*)d_in[0];
  const float* Wq = (const float*)d_in[1];
  const float* bq = (const float*)d_in[2];
  const float* Wk = (const float*)d_in[3];
  const float* bk = (const float*)d_in[4];
  const float* Wv = (const float*)d_in[5];
  const float* bv = (const float*)d_in[6];
  const float* Wp = (const float*)d_in[7];
  const float* bp = (const float*)d_in[8];
  float* out = (float*)d_out;

  char* ws = (char*)d_ws;
  const size_t MB = 1024 * 1024;
  bf16*  xb    = (bf16*)(ws);             // 8 MB [4096][1024]; reused as att
  bf16*  wqkvT = (bf16*)(ws + 8 * MB);    // 6 MB [3072][1024]
  bf16*  wpT   = (bf16*)(ws + 14 * MB);   // 2 MB [1024][1024]
  float* bcat  = (float*)(ws + 16 * MB);  // 12 KB
  bf16*  qkv   = (bf16*)(ws + 17 * MB);   // 24 MB [4096][3072]
  bf16*  vtr   = (bf16*)(ws + 41 * MB);   // 8 MB [2][16][64][2048]
  bf16*  att   = xb;                      // alias: xb dead after QKV GEMM

  k_cvt_bf16<<<2048, 256, 0, stream>>>(x, xb, 524288);
  k_wt<<<512, 256, 0, stream>>>(Wq, wqkvT);
  k_wt<<<512, 256, 0, stream>>>(Wk, wqkvT + 1024 * 1024);
  k_wt<<<512, 256, 0, stream>>>(Wv, wqkvT + 2 * 1024 * 1024);
  k_wt<<<512, 256, 0, stream>>>(Wp, wpT);
  k_bcat<<<12, 256, 0, stream>>>(bq, bk, bv, bcat);

  k_gemm_bt<bf16><<<dim3(32, 24), 256, 0, stream>>>(xb, wqkvT, bcat, qkv, 1024, 3072);
  k_transpose_v<<<2048, 256, 0, stream>>>(qkv, vtr);
  k_attn<<<1024, 256, 0, stream>>>(qkv, vtr, att);
  k_gemm_bt<float><<<dim3(32, 8), 256, 0, stream>>>(att, wpT, bp, out, 1024, 1024);
}

// Round 2
// 219.898 us; speedup vs baseline: 1.4621x; 1.4621x over previous
//
#include <hip/hip_runtime.h>

#define AS_GLOBAL __attribute__((address_space(1)))
#define AS_LDS    __attribute__((address_space(3)))

typedef __bf16 bf16;
typedef __bf16 bf16x8 __attribute__((ext_vector_type(8)));
typedef float  f32x4  __attribute__((ext_vector_type(4)));

__device__ __forceinline__ void gload16(const void* g, void* l) {
  __builtin_amdgcn_global_load_lds((const AS_GLOBAL unsigned int*)g,
                                   (AS_LDS unsigned int*)l, 16, 0, 0);
}

// swizzled LDS address for a [R][128B] row-major tile:
// stored_byte = row*128 + (bytecol ^ ((row&7)<<4))
__device__ __forceinline__ void* swz(void* base, int row, int bytecol) {
  return (char*)base + row * 128 + (bytecol ^ ((row & 7) << 4));
}

// ---------------- prep kernels ----------------

__global__ __launch_bounds__(256) void k_cvt_bf16(const float* __restrict__ x,
                                                  bf16* __restrict__ o, int n8) {
  int i = blockIdx.x * blockDim.x + threadIdx.x;
  if (i >= n8) return;
  const float4* p = (const float4*)(x + (size_t)i * 8);
  float4 a = p[0], b = p[1];
  bf16x8 v;
  v[0] = (bf16)a.x; v[1] = (bf16)a.y; v[2] = (bf16)a.z; v[3] = (bf16)a.w;
  v[4] = (bf16)b.x; v[5] = (bf16)b.y; v[6] = (bf16)b.z; v[7] = (bf16)b.w;
  *(bf16x8*)(o + (size_t)i * 8) = v;
}

// W [K=1024][N=1024] fp32 (in,out) -> WT [N][K] bf16
__global__ __launch_bounds__(256) void k_wt(const float* __restrict__ W,
                                            bf16* __restrict__ WT) {
  int lin = blockIdx.x * blockDim.x + threadIdx.x;
  int n  = lin & 1023;
  int kc = lin >> 10;
  bf16x8 v;
#pragma unroll
  for (int j = 0; j < 8; ++j) v[j] = (bf16)W[(size_t)(kc * 8 + j) * 1024 + n];
  *(bf16x8*)&WT[(size_t)n * 1024 + kc * 8] = v;
}

__global__ __launch_bounds__(256) void k_bcat(const float* __restrict__ bq,
                                              const float* __restrict__ bk,
                                              const float* __restrict__ bv,
                                              float* __restrict__ bc) {
  int i = blockIdx.x * blockDim.x + threadIdx.x;
  if (i < 1024) bc[i] = bq[i];
  else if (i < 2048) bc[i] = bk[i - 1024];
  else if (i < 3072) bc[i] = bv[i - 2048];
}

// V region of qkv [4096][3072] -> Vt [b][h][d=64][t=2048] bf16
__global__ __launch_bounds__(256) void k_transpose_v(const bf16* __restrict__ qkv,
                                                     bf16* __restrict__ vt) {
  int blk = blockIdx.x;
  int tc = blk & 63, h = (blk >> 6) & 15, b = blk >> 10;
  int d = threadIdx.x & 63, tq = threadIdx.x >> 6;
  int t0 = tc * 32 + tq * 8;
  bf16x8 v;
#pragma unroll
  for (int j = 0; j < 8; ++j)
    v[j] = qkv[(size_t)(b * 2048 + t0 + j) * 3072 + 2048 + h * 64 + d];
  *(bf16x8*)&vt[((size_t)(b * 16 + h) * 64 + d) * 2048 + t0] = v;
}

// ---------------- GEMM: C[M,N] = A[M,K] @ Bt[N,K]^T + bias ----------------
template <typename OutT>
__global__ __launch_bounds__(256) void k_gemm_bt(const bf16* __restrict__ A,
                                                 const bf16* __restrict__ Bt,
                                                 const float* __restrict__ bias,
                                                 OutT* __restrict__ C,
                                                 int K, int N) {
  __shared__ bf16 As[128 * 32];
  __shared__ bf16 Bs[128 * 32];
  const int tid = threadIdx.x;
  const int w = tid >> 6, l = tid & 63, g = l >> 4, c = l & 15;
  const int wr = w >> 1, wc = w & 1;
  const int row0 = blockIdx.x * 128, col0 = blockIdx.y * 128;
  f32x4 acc[4][4] = {};

  for (int k0 = 0; k0 < K; k0 += 32) {
#pragma unroll
    for (int it = 0; it < 2; ++it) {
      int idx = it * 256 + tid;
      int r = idx >> 2, cc = idx & 3;
      gload16(A  + (size_t)(row0 + r) * K + k0 + cc * 8, &As[idx * 8]);
      gload16(Bt + (size_t)(col0 + r) * K + k0 + cc * 8, &Bs[idx * 8]);
    }
    __syncthreads();
    bf16x8 af[4], bfr[4];
#pragma unroll
    for (int m = 0; m < 4; ++m)
      af[m] = *(const bf16x8*)&As[(wr * 64 + m * 16 + c) * 32 + g * 8];
#pragma unroll
    for (int n = 0; n < 4; ++n)
      bfr[n] = *(const bf16x8*)&Bs[(wc * 64 + n * 16 + c) * 32 + g * 8];
#pragma unroll
    for (int m = 0; m < 4; ++m)
#pragma unroll
      for (int n = 0; n < 4; ++n)
        acc[m][n] = __builtin_amdgcn_mfma_f32_16x16x32_bf16(af[m], bfr[n],
                                                            acc[m][n], 0, 0, 0);
    __syncthreads();
  }

#pragma unroll
  for (int m = 0; m < 4; ++m) {
    int row = row0 + wr * 64 + m * 16 + g * 4;
#pragma unroll
    for (int n = 0; n < 4; ++n) {
      int col = col0 + wc * 64 + n * 16 + c;
      float bv = bias[col];
#pragma unroll
      for (int r = 0; r < 4; ++r) {
        float v = acc[m][n][r] + bv;
        C[(size_t)(row + r) * N + col] = (OutT)v;
      }
    }
  }
}

// ---------------- flash attention, LDS-staged KV, double-buffered ----------
// grid: (b, h, qtile of 64). 4 waves x 16 q-rows each. KV tiles of 64.
// mask: valid iff s <= q && !(s % 3 == 1 && s >= 4)
__global__ __launch_bounds__(256) void k_attn(const bf16* __restrict__ qkv,
                                              const bf16* __restrict__ vt,
                                              bf16* __restrict__ att) {
  const int blk = blockIdx.x;
  const int qt = blk & 31, h = (blk >> 5) & 15, b = blk >> 9;
  const int tid = threadIdx.x;
  const int w = tid >> 6, l = tid & 63, g = l >> 4, c = l & 15;
  const int q0 = qt * 64, qw0 = q0 + w * 16;

  __shared__ bf16 Ks[2][64 * 64];  // [s][d], swizzled rows of 128B
  __shared__ bf16 Vs[2][64 * 64];  // [d][s], swizzled rows of 128B
  __shared__ bf16 Plds[4][16 * 64];  // per-wave [q][s], swizzled

  const bf16* kg = qkv + (size_t)(b * 2048) * 3072 + 1024 + h * 64;
  const bf16* vg = vt + (size_t)(b * 16 + h) * 64 * 2048;

  // Q A-frags (row=c, k=g*8+j), D=64 -> two k-chunks
  const bf16* qb = qkv + (size_t)(b * 2048 + qw0 + c) * 3072 + h * 64 + g * 8;
  bf16x8 qf0 = *(const bf16x8*)qb;
  bf16x8 qf1 = *(const bf16x8*)(qb + 32);

  f32x4 o[4] = {};
  float mrow[4] = {-1e30f, -1e30f, -1e30f, -1e30f};
  float ell[4] = {0.f, 0.f, 0.f, 0.f};

  const int nt = qt + 1;

  // stage tile t into buf: K rows (s, 128B) and V rows (d, 128B),
  // source pre-swizzled so (linear LDS dest) xor (swizzled read) agree.
  auto stage = [&](int buf, int t) {
    int s0 = t * 64;
#pragma unroll
    for (int it = 0; it < 2; ++it) {
      int ch = it * 256 + tid;          // 16B chunk id, 0..511
      int r = ch >> 3, j = ch & 7;
      int jj = j ^ (r & 7);             // pre-swizzled source chunk
      gload16(kg + (size_t)(s0 + r) * 3072 + jj * 8, &Ks[buf][ch * 8]);
      gload16(vg + (size_t)r * 2048 + s0 + jj * 8, &Vs[buf][ch * 8]);
    }
  };

  stage(0, 0);
  __syncthreads();
  int cur = 0;

  for (int t = 0; t < nt; ++t) {
    if (t + 1 < nt) stage(cur ^ 1, t + 1);
    const int s0 = t * 64;

    // S = Q K^T : 4 s-subtiles x 2 k-chunks
    f32x4 ss[4] = {};
#pragma unroll
    for (int st = 0; st < 4; ++st) {
      bf16x8 ka = *(const bf16x8*)swz(&Ks[cur][0], st * 16 + c, g * 16);
      bf16x8 kb2 = *(const bf16x8*)swz(&Ks[cur][0], st * 16 + c, 64 + g * 16);
      ss[st] = __builtin_amdgcn_mfma_f32_16x16x32_bf16(qf0, ka,  ss[st], 0, 0, 0);
      ss[st] = __builtin_amdgcn_mfma_f32_16x16x32_bf16(qf1, kb2, ss[st], 0, 0, 0);
    }

    // mask + scale (C-layout: row q = g*4+r, col s = s0 + st*16 + c)
    const int sc = s0 + c;
    bool cm[4];
#pragma unroll
    for (int st = 0; st < 4; ++st) {
      int s = sc + st * 16;
      cm[st] = ((s % 3) == 1) && (s >= 4);
    }
    float mx[4];
#pragma unroll
    for (int r = 0; r < 4; ++r) {
      int q = qw0 + g * 4 + r;
      float m = -1e30f;
#pragma unroll
      for (int st = 0; st < 4; ++st) {
        int s = sc + st * 16;
        float v = (!cm[st] && s <= q) ? ss[st][r] * 0.125f : -1e30f;
        ss[st][r] = v;
        m = fmaxf(m, v);
      }
      mx[r] = m;
    }
#pragma unroll
    for (int r = 0; r < 4; ++r) {
      mx[r] = fmaxf(mx[r], __shfl_xor(mx[r], 1));
      mx[r] = fmaxf(mx[r], __shfl_xor(mx[r], 2));
      mx[r] = fmaxf(mx[r], __shfl_xor(mx[r], 4));
      mx[r] = fmaxf(mx[r], __shfl_xor(mx[r], 8));
    }
    float al[4];
#pragma unroll
    for (int r = 0; r < 4; ++r) {
      float mn = fmaxf(mrow[r], mx[r]);
      al[r] = __expf(mrow[r] - mn);
      mrow[r] = mn;
      float rsum = 0.f;
#pragma unroll
      for (int st = 0; st < 4; ++st) {
        float p = __expf(ss[st][r] - mn);
        rsum += p;
        *(bf16*)swz(&Plds[w][0], g * 4 + r, st * 32 + c * 2) = (bf16)p;
      }
      rsum += __shfl_xor(rsum, 1);
      rsum += __shfl_xor(rsum, 2);
      rsum += __shfl_xor(rsum, 4);
      rsum += __shfl_xor(rsum, 8);
      ell[r] = ell[r] * al[r] + rsum;
    }
#pragma unroll
    for (int dc = 0; dc < 4; ++dc)
#pragma unroll
      for (int r = 0; r < 4; ++r) o[dc][r] *= al[r];

    // wait cross-lane P writes (wave-private LDS): rule #18 fence pair
    asm volatile("s_waitcnt lgkmcnt(0)" ::: "memory");
    __builtin_amdgcn_sched_barrier(0);

    // O += P @ V : A-frag P[q][s], B-frag V[d][s] (both swizzled reads)
#pragma unroll
    for (int kk = 0; kk < 2; ++kk) {
      bf16x8 pf = *(const bf16x8*)swz(&Plds[w][0], c, kk * 64 + g * 16);
#pragma unroll
      for (int dc = 0; dc < 4; ++dc) {
        bf16x8 vf = *(const bf16x8*)swz(&Vs[cur][0], dc * 16 + c, kk * 64 + g * 16);
        o[dc] = __builtin_amdgcn_mfma_f32_16x16x32_bf16(pf, vf, o[dc], 0, 0, 0);
      }
    }
    __syncthreads();   // staged loads for next tile drained; buf safe to flip
    cur ^= 1;
  }

#pragma unroll
  for (int dc = 0; dc < 4; ++dc)
#pragma unroll
    for (int r = 0; r < 4; ++r) {
      int q = qw0 + g * 4 + r;
      att[(size_t)(b * 2048 + q) * 1024 + h * 64 + dc * 16 + c] =
          (bf16)(o[dc][r] / ell[r]);
    }
}

// ---------------- launcher ----------------
extern "C" void kernel_launch(void* const* d_in, const int* in_sizes, int n_in,
                              void* d_out, int out_size, void* d_ws, size_t ws_size,
                              hipStream_t stream) {
  const float* x  = (const float*)d_in[0];
  const float* Wq = (const float*)d_in[1];
  const float* bq = (const float*)d_in[2];
  const float* Wk = (const float*)d_in[3];
  const float* bk = (const float*)d_in[4];
  const float* Wv = (const float*)d_in[5];
  const float* bv = (const float*)d_in[6];
  const float* Wp = (const float*)d_in[7];
  const float* bp = (const float*)d_in[8];
  float* out = (float*)d_out;

  char* ws = (char*)d_ws;
  const size_t MB = 1024 * 1024;
  bf16*  xb    = (bf16*)(ws);             // 8 MB [4096][1024]; reused as att
  bf16*  wqkvT = (bf16*)(ws + 8 * MB);    // 6 MB [3072][1024]
  bf16*  wpT   = (bf16*)(ws + 14 * MB);   // 2 MB [1024][1024]
  float* bcat  = (float*)(ws + 16 * MB);  // 12 KB
  bf16*  qkv   = (bf16*)(ws + 17 * MB);   // 24 MB [4096][3072]
  bf16*  vtr   = (bf16*)(ws + 41 * MB);   // 8 MB [2][16][64][2048]
  bf16*  att   = xb;                      // alias: xb dead after QKV GEMM

  k_cvt_bf16<<<2048, 256, 0, stream>>>(x, xb, 524288);
  k_wt<<<512, 256, 0, stream>>>(Wq, wqkvT);
  k_wt<<<512, 256, 0, stream>>>(Wk, wqkvT + 1024 * 1024);
  k_wt<<<512, 256, 0, stream>>>(Wv, wqkvT + 2 * 1024 * 1024);
  k_wt<<<512, 256, 0, stream>>>(Wp, wpT);
  k_bcat<<<12, 256, 0, stream>>>(bq, bk, bv, bcat);

  k_gemm_bt<bf16><<<dim3(32, 24), 256, 0, stream>>>(xb, wqkvT, bcat, qkv, 1024, 3072);
  k_transpose_v<<<2048, 256, 0, stream>>>(qkv, vtr);
  k_attn<<<1024, 256, 0, stream>>>(qkv, vtr, att);
  k_gemm_bt<float><<<dim3(32, 8), 256, 0, stream>>>(att, wpT, bp, out, 1024, 1024);
}

// Round 3
// 165.929 us; speedup vs baseline: 1.9376x; 1.3253x over previous
//
#include <hip/hip_runtime.h>

#define AS_GLOBAL __attribute__((address_space(1)))
#define AS_LDS    __attribute__((address_space(3)))

typedef __bf16 bf16;
typedef __bf16 bf16x8 __attribute__((ext_vector_type(8)));
typedef float  f32x4  __attribute__((ext_vector_type(4)));

__device__ __forceinline__ void gload16(const void* g, void* l) {
  __builtin_amdgcn_global_load_lds((const AS_GLOBAL unsigned int*)g,
                                   (AS_LDS unsigned int*)l, 16, 0, 0);
}

// swizzled LDS address for a [R][128B] row-major tile:
// stored_byte = row*128 + (bytecol ^ ((row&7)<<4))
__device__ __forceinline__ void* swz(void* base, int row, int bytecol) {
  return (char*)base + row * 128 + (bytecol ^ ((row & 7) << 4));
}

// ---------------- prep kernels ----------------

__global__ __launch_bounds__(256) void k_cvt_bf16(const float* __restrict__ x,
                                                  bf16* __restrict__ o, int n8) {
  int i = blockIdx.x * blockDim.x + threadIdx.x;
  if (i >= n8) return;
  const float4* p = (const float4*)(x + (size_t)i * 8);
  float4 a = p[0], b = p[1];
  bf16x8 v;
  v[0] = (bf16)a.x; v[1] = (bf16)a.y; v[2] = (bf16)a.z; v[3] = (bf16)a.w;
  v[4] = (bf16)b.x; v[5] = (bf16)b.y; v[6] = (bf16)b.z; v[7] = (bf16)b.w;
  *(bf16x8*)(o + (size_t)i * 8) = v;
}

// W [K=1024][N=1024] fp32 (in,out) -> WT [N][K] bf16
__global__ __launch_bounds__(256) void k_wt(const float* __restrict__ W,
                                            bf16* __restrict__ WT) {
  int lin = blockIdx.x * blockDim.x + threadIdx.x;
  int n  = lin & 1023;
  int kc = lin >> 10;
  bf16x8 v;
#pragma unroll
  for (int j = 0; j < 8; ++j) v[j] = (bf16)W[(size_t)(kc * 8 + j) * 1024 + n];
  *(bf16x8*)&WT[(size_t)n * 1024 + kc * 8] = v;
}

__global__ __launch_bounds__(256) void k_bcat(const float* __restrict__ bq,
                                              const float* __restrict__ bk,
                                              const float* __restrict__ bv,
                                              float* __restrict__ bc) {
  int i = blockIdx.x * blockDim.x + threadIdx.x;
  if (i < 1024) bc[i] = bq[i];
  else if (i < 2048) bc[i] = bk[i - 1024];
  else if (i < 3072) bc[i] = bv[i - 2048];
}

// V region of qkv [4096][3072] -> Vt [b][h][d=64][t=2048] bf16
__global__ __launch_bounds__(256) void k_transpose_v(const bf16* __restrict__ qkv,
                                                     bf16* __restrict__ vt) {
  int blk = blockIdx.x;
  int tc = blk & 63, h = (blk >> 6) & 15, b = blk >> 10;
  int d = threadIdx.x & 63, tq = threadIdx.x >> 6;
  int t0 = tc * 32 + tq * 8;
  bf16x8 v;
#pragma unroll
  for (int j = 0; j < 8; ++j)
    v[j] = qkv[(size_t)(b * 2048 + t0 + j) * 3072 + 2048 + h * 64 + d];
  *(bf16x8*)&vt[((size_t)(b * 16 + h) * 64 + d) * 2048 + t0] = v;
}

// ---------------- GEMM: C[M,N] = A[M,K] @ Bt[N,K]^T + bias ----------------
template <typename OutT>
__global__ __launch_bounds__(256) void k_gemm_bt(const bf16* __restrict__ A,
                                                 const bf16* __restrict__ Bt,
                                                 const float* __restrict__ bias,
                                                 OutT* __restrict__ C,
                                                 int K, int N) {
  __shared__ bf16 As[128 * 32];
  __shared__ bf16 Bs[128 * 32];
  const int tid = threadIdx.x;
  const int w = tid >> 6, l = tid & 63, g = l >> 4, c = l & 15;
  const int wr = w >> 1, wc = w & 1;
  const int row0 = blockIdx.x * 128, col0 = blockIdx.y * 128;
  f32x4 acc[4][4] = {};

  for (int k0 = 0; k0 < K; k0 += 32) {
#pragma unroll
    for (int it = 0; it < 2; ++it) {
      int idx = it * 256 + tid;
      int r = idx >> 2, cc = idx & 3;
      gload16(A  + (size_t)(row0 + r) * K + k0 + cc * 8, &As[idx * 8]);
      gload16(Bt + (size_t)(col0 + r) * K + k0 + cc * 8, &Bs[idx * 8]);
    }
    __syncthreads();
    bf16x8 af[4], bfr[4];
#pragma unroll
    for (int m = 0; m < 4; ++m)
      af[m] = *(const bf16x8*)&As[(wr * 64 + m * 16 + c) * 32 + g * 8];
#pragma unroll
    for (int n = 0; n < 4; ++n)
      bfr[n] = *(const bf16x8*)&Bs[(wc * 64 + n * 16 + c) * 32 + g * 8];
#pragma unroll
    for (int m = 0; m < 4; ++m)
#pragma unroll
      for (int n = 0; n < 4; ++n)
        acc[m][n] = __builtin_amdgcn_mfma_f32_16x16x32_bf16(af[m], bfr[n],
                                                            acc[m][n], 0, 0, 0);
    __syncthreads();
  }

#pragma unroll
  for (int m = 0; m < 4; ++m) {
    int row = row0 + wr * 64 + m * 16 + g * 4;
#pragma unroll
    for (int n = 0; n < 4; ++n) {
      int col = col0 + wc * 64 + n * 16 + c;
      float bv = bias[col];
#pragma unroll
      for (int r = 0; r < 4; ++r) {
        float v = acc[m][n][r] + bv;
        C[(size_t)(row + r) * N + col] = (OutT)v;
      }
    }
  }
}

// ---------------- flash attention v3 --------------------------------------
// 512 blocks, each = q-tile pair (p, 31-p) => uniform 33 KV-tiles/block.
// 4 waves x 16 q-rows. 3-buffer KV pipeline, raw s_barrier + counted vmcnt.
// mask: valid iff s <= q && !(s % 3 == 1 && s >= 4)
__global__ __launch_bounds__(256) void k_attn(const bf16* __restrict__ qkv,
                                              const bf16* __restrict__ vt,
                                              bf16* __restrict__ att) {
  // XCD-aware bijective swizzle (512 = 8 XCD * 64)
  const int bid = ((blockIdx.x & 7) << 6) | (blockIdx.x >> 3);
  const int p = bid & 15, h = (bid >> 4) & 15, b = bid >> 8;
  const int tid = threadIdx.x;
  const int w = tid >> 6, l = tid & 63, g = l >> 4, c = l & 15;

  __shared__ bf16 Ks[3][64 * 64];    // [s][d] swizzled 128B rows
  __shared__ bf16 Vs[3][64 * 64];    // [d][s] swizzled 128B rows
  __shared__ bf16 Plds[4][16 * 64];  // per-wave [q][s] swizzled

  const bf16* kg = qkv + (size_t)(b * 2048) * 3072 + 1024 + h * 64;
  const bf16* vg = vt + (size_t)(b * 16 + h) * 64 * 2048;

  // stage KV tile t into buf (source pre-swizzled, dest linear)
  auto stage = [&](int buf, int t) {
    int s0 = t * 64;
#pragma unroll
    for (int it = 0; it < 2; ++it) {
      int ch = it * 256 + tid;
      int r = ch >> 3, j = ch & 7;
      int jj = j ^ (r & 7);
      gload16(kg + (size_t)(s0 + r) * 3072 + jj * 8, &Ks[buf][ch * 8]);
      gload16(vg + (size_t)r * 2048 + s0 + jj * 8, &Vs[buf][ch * 8]);
    }
  };

#pragma unroll 1
  for (int seg = 0; seg < 2; ++seg) {
    const int qt = (seg == 0) ? p : 31 - p;
    const int qw0 = qt * 64 + w * 16;
    const int nt = qt + 1;

    // Q A-frags, pre-scaled by 1/sqrt(64)=0.125 (exact in bf16)
    const bf16* qb = qkv + (size_t)(b * 2048 + qw0 + c) * 3072 + h * 64 + g * 8;
    bf16x8 qf0 = *(const bf16x8*)qb;
    bf16x8 qf1 = *(const bf16x8*)(qb + 32);
#pragma unroll
    for (int j = 0; j < 8; ++j) {
      qf0[j] = (bf16)((float)qf0[j] * 0.125f);
      qf1[j] = (bf16)((float)qf1[j] * 0.125f);
    }

    f32x4 o[4] = {};
    float mrow[4] = {-1e30f, -1e30f, -1e30f, -1e30f};
    float ell[4] = {0.f, 0.f, 0.f, 0.f};

    stage(0, 0);
    if (nt > 1) stage(1, 1);

    int cur = 0;
#pragma unroll 1
    for (int t = 0; t < nt; ++t) {
      // wait for own share of stage(t): in-order vmcnt retirement means
      // <=4 outstanding ==> all but the newest stage are complete.
      if (t + 1 < nt) { asm volatile("s_waitcnt vmcnt(4)" ::: "memory"); }
      else            { asm volatile("s_waitcnt vmcnt(0)" ::: "memory"); }
      __builtin_amdgcn_sched_barrier(0);
      __builtin_amdgcn_s_barrier();       // tile t visible to all waves;
      __builtin_amdgcn_sched_barrier(0);  // all waves done with tile t-1

      if (t + 2 < nt) {
        int b2 = cur + 2; if (b2 >= 3) b2 -= 3;
        stage(b2, t + 2);                 // overwrites buf of tile t-1: safe
      }

      // ---- S = Q K^T ----
      f32x4 ss[4] = {};
#pragma unroll
      for (int st = 0; st < 4; ++st) {
        bf16x8 ka  = *(const bf16x8*)swz(&Ks[cur][0], st * 16 + c, g * 16);
        bf16x8 kb2 = *(const bf16x8*)swz(&Ks[cur][0], st * 16 + c, 64 + g * 16);
        ss[st] = __builtin_amdgcn_mfma_f32_16x16x32_bf16(qf0, ka,  ss[st], 0, 0, 0);
        ss[st] = __builtin_amdgcn_mfma_f32_16x16x32_bf16(qf1, kb2, ss[st], 0, 0, 0);
      }

      // ---- mask ----
      const int sc = t * 64 + c;
      const bool diag = (t == qt);
      bool cm[4];
#pragma unroll
      for (int st = 0; st < 4; ++st) {
        int s = sc + st * 16;
        cm[st] = ((s % 3) == 1) && (s >= 4);
      }
      float mx[4];
#pragma unroll
      for (int r = 0; r < 4; ++r) {
        int q = qw0 + g * 4 + r;
        float m = -1e30f;
#pragma unroll
        for (int st = 0; st < 4; ++st) {
          int s = sc + st * 16;
          bool ok = !cm[st] && (!diag || s <= q);
          float v = ok ? ss[st][r] : -1e30f;
          ss[st][r] = v;
          m = fmaxf(m, v);
        }
        mx[r] = m;
      }
      // ---- online softmax (16-lane column groups) ----
#pragma unroll
      for (int r = 0; r < 4; ++r) {
        mx[r] = fmaxf(mx[r], __shfl_xor(mx[r], 1));
        mx[r] = fmaxf(mx[r], __shfl_xor(mx[r], 2));
        mx[r] = fmaxf(mx[r], __shfl_xor(mx[r], 4));
        mx[r] = fmaxf(mx[r], __shfl_xor(mx[r], 8));
      }
      float al[4];
#pragma unroll
      for (int r = 0; r < 4; ++r) {
        float mn = fmaxf(mrow[r], mx[r]);
        al[r] = __expf(mrow[r] - mn);
        mrow[r] = mn;
        float rsum = 0.f;
#pragma unroll
        for (int st = 0; st < 4; ++st) {
          float pv = __expf(ss[st][r] - mn);
          rsum += pv;
          *(bf16*)swz(&Plds[w][0], g * 4 + r, st * 32 + c * 2) = (bf16)pv;
        }
        rsum += __shfl_xor(rsum, 1);
        rsum += __shfl_xor(rsum, 2);
        rsum += __shfl_xor(rsum, 4);
        rsum += __shfl_xor(rsum, 8);
        ell[r] = ell[r] * al[r] + rsum;
      }
#pragma unroll
      for (int dc = 0; dc < 4; ++dc)
#pragma unroll
        for (int r = 0; r < 4; ++r) o[dc][r] *= al[r];

      // wave-private P round trip (rule #18 fence pair)
      asm volatile("s_waitcnt lgkmcnt(0)" ::: "memory");
      __builtin_amdgcn_sched_barrier(0);

      // ---- O += P @ V ----
#pragma unroll
      for (int kk = 0; kk < 2; ++kk) {
        bf16x8 pf = *(const bf16x8*)swz(&Plds[w][0], c, kk * 64 + g * 16);
#pragma unroll
        for (int dc = 0; dc < 4; ++dc) {
          bf16x8 vf = *(const bf16x8*)swz(&Vs[cur][0], dc * 16 + c, kk * 64 + g * 16);
          o[dc] = __builtin_amdgcn_mfma_f32_16x16x32_bf16(pf, vf, o[dc], 0, 0, 0);
        }
      }

      ++cur; if (cur >= 3) cur -= 3;
    }

    // ---- epilogue ----
#pragma unroll
    for (int dc = 0; dc < 4; ++dc)
#pragma unroll
      for (int r = 0; r < 4; ++r) {
        int q = qw0 + g * 4 + r;
        att[(size_t)(b * 2048 + q) * 1024 + h * 64 + dc * 16 + c] =
            (bf16)(o[dc][r] / ell[r]);
      }

    // protect LDS bufs before next segment's prologue staging
    __builtin_amdgcn_s_barrier();
  }
}

// ---------------- launcher ----------------
extern "C" void kernel_launch(void* const* d_in, const int* in_sizes, int n_in,
                              void* d_out, int out_size, void* d_ws, size_t ws_size,
                              hipStream_t stream) {
  const float* x  = (const float*)d_in[0];
  const float* Wq = (const float*)d_in[1];
  const float* bq = (const float*)d_in[2];
  const float* Wk = (const float*)d_in[3];
  const float* bk = (const float*)d_in[4];
  const float* Wv = (const float*)d_in[5];
  const float* bv = (const float*)d_in[6];
  const float* Wp = (const float*)d_in[7];
  const float* bp = (const float*)d_in[8];
  float* out = (float*)d_out;

  char* ws = (char*)d_ws;
  const size_t MB = 1024 * 1024;
  bf16*  xb    = (bf16*)(ws);             // 8 MB [4096][1024]; reused as att
  bf16*  wqkvT = (bf16*)(ws + 8 * MB);    // 6 MB [3072][1024]
  bf16*  wpT   = (bf16*)(ws + 14 * MB);   // 2 MB [1024][1024]
  float* bcat  = (float*)(ws + 16 * MB);  // 12 KB
  bf16*  qkv   = (bf16*)(ws + 17 * MB);   // 24 MB [4096][3072]
  bf16*  vtr   = (bf16*)(ws + 41 * MB);   // 8 MB [2][16][64][2048]
  bf16*  att   = xb;                      // alias: xb dead after QKV GEMM

  k_cvt_bf16<<<2048, 256, 0, stream>>>(x, xb, 524288);
  k_wt<<<512, 256, 0, stream>>>(Wq, wqkvT);
  k_wt<<<512, 256, 0, stream>>>(Wk, wqkvT + 1024 * 1024);
  k_wt<<<512, 256, 0, stream>>>(Wv, wqkvT + 2 * 1024 * 1024);
  k_wt<<<512, 256, 0, stream>>>(Wp, wpT);
  k_bcat<<<12, 256, 0, stream>>>(bq, bk, bv, bcat);

  k_gemm_bt<bf16><<<dim3(32, 24), 256, 0, stream>>>(xb, wqkvT, bcat, qkv, 1024, 3072);
  k_transpose_v<<<2048, 256, 0, stream>>>(qkv, vtr);
  k_attn<<<512, 256, 0, stream>>>(qkv, vtr, att);
  k_gemm_bt<float><<<dim3(32, 8), 256, 0, stream>>>(att, wpT, bp, out, 1024, 1024);
}

// Round 4
// 158.872 us; speedup vs baseline: 2.0237x; 1.0444x over previous
//
#include <hip/hip_runtime.h>

#define AS_GLOBAL __attribute__((address_space(1)))
#define AS_LDS    __attribute__((address_space(3)))

typedef __bf16 bf16;
typedef __bf16 bf16x8 __attribute__((ext_vector_type(8)));
typedef float  f32x4  __attribute__((ext_vector_type(4)));

__device__ __forceinline__ void gload16(const void* g, void* l) {
  __builtin_amdgcn_global_load_lds((const AS_GLOBAL unsigned int*)g,
                                   (AS_LDS unsigned int*)l, 16, 0, 0);
}

// swizzled LDS address for a [R][128B] row-major tile:
// stored_byte = row*128 + (bytecol ^ ((row&7)<<4))
__device__ __forceinline__ void* swz(void* base, int row, int bytecol) {
  return (char*)base + row * 128 + (bytecol ^ ((row & 7) << 4));
}

// ---------------- prep kernels ----------------

__global__ __launch_bounds__(256) void k_cvt_bf16(const float* __restrict__ x,
                                                  bf16* __restrict__ o, int n8) {
  int i = blockIdx.x * blockDim.x + threadIdx.x;
  if (i >= n8) return;
  const float4* p = (const float4*)(x + (size_t)i * 8);
  float4 a = p[0], b = p[1];
  bf16x8 v;
  v[0] = (bf16)a.x; v[1] = (bf16)a.y; v[2] = (bf16)a.z; v[3] = (bf16)a.w;
  v[4] = (bf16)b.x; v[5] = (bf16)b.y; v[6] = (bf16)b.z; v[7] = (bf16)b.w;
  *(bf16x8*)(o + (size_t)i * 8) = v;
}

// W [K=1024][N=1024] fp32 (in,out) -> WT [N][K] bf16
__global__ __launch_bounds__(256) void k_wt(const float* __restrict__ W,
                                            bf16* __restrict__ WT) {
  int lin = blockIdx.x * blockDim.x + threadIdx.x;
  int n  = lin & 1023;
  int kc = lin >> 10;
  bf16x8 v;
#pragma unroll
  for (int j = 0; j < 8; ++j) v[j] = (bf16)W[(size_t)(kc * 8 + j) * 1024 + n];
  *(bf16x8*)&WT[(size_t)n * 1024 + kc * 8] = v;
}

__global__ __launch_bounds__(256) void k_bcat(const float* __restrict__ bq,
                                              const float* __restrict__ bk,
                                              const float* __restrict__ bv,
                                              float* __restrict__ bc) {
  int i = blockIdx.x * blockDim.x + threadIdx.x;
  if (i < 1024) bc[i] = bq[i];
  else if (i < 2048) bc[i] = bk[i - 1024];
  else if (i < 3072) bc[i] = bv[i - 2048];
}

// V region of qkv [4096][3072] -> Vt [b][h][d=64][t=2048] bf16
__global__ __launch_bounds__(256) void k_transpose_v(const bf16* __restrict__ qkv,
                                                     bf16* __restrict__ vt) {
  int blk = blockIdx.x;
  int tc = blk & 63, h = (blk >> 6) & 15, b = blk >> 10;
  int d = threadIdx.x & 63, tq = threadIdx.x >> 6;
  int t0 = tc * 32 + tq * 8;
  bf16x8 v;
#pragma unroll
  for (int j = 0; j < 8; ++j)
    v[j] = qkv[(size_t)(b * 2048 + t0 + j) * 3072 + 2048 + h * 64 + d];
  *(bf16x8*)&vt[((size_t)(b * 16 + h) * 64 + d) * 2048 + t0] = v;
}

// ---------------- GEMM: C[M,N] = A[M,K] @ Bt[N,K]^T + bias ----------------
template <typename OutT>
__global__ __launch_bounds__(256) void k_gemm_bt(const bf16* __restrict__ A,
                                                 const bf16* __restrict__ Bt,
                                                 const float* __restrict__ bias,
                                                 OutT* __restrict__ C,
                                                 int K, int N) {
  __shared__ bf16 As[128 * 32];
  __shared__ bf16 Bs[128 * 32];
  const int tid = threadIdx.x;
  const int w = tid >> 6, l = tid & 63, g = l >> 4, c = l & 15;
  const int wr = w >> 1, wc = w & 1;
  const int row0 = blockIdx.x * 128, col0 = blockIdx.y * 128;
  f32x4 acc[4][4] = {};

  for (int k0 = 0; k0 < K; k0 += 32) {
#pragma unroll
    for (int it = 0; it < 2; ++it) {
      int idx = it * 256 + tid;
      int r = idx >> 2, cc = idx & 3;
      gload16(A  + (size_t)(row0 + r) * K + k0 + cc * 8, &As[idx * 8]);
      gload16(Bt + (size_t)(col0 + r) * K + k0 + cc * 8, &Bs[idx * 8]);
    }
    __syncthreads();
    bf16x8 af[4], bfr[4];
#pragma unroll
    for (int m = 0; m < 4; ++m)
      af[m] = *(const bf16x8*)&As[(wr * 64 + m * 16 + c) * 32 + g * 8];
#pragma unroll
    for (int n = 0; n < 4; ++n)
      bfr[n] = *(const bf16x8*)&Bs[(wc * 64 + n * 16 + c) * 32 + g * 8];
#pragma unroll
    for (int m = 0; m < 4; ++m)
#pragma unroll
      for (int n = 0; n < 4; ++n)
        acc[m][n] = __builtin_amdgcn_mfma_f32_16x16x32_bf16(af[m], bfr[n],
                                                            acc[m][n], 0, 0, 0);
    __syncthreads();
  }

#pragma unroll
  for (int m = 0; m < 4; ++m) {
    int row = row0 + wr * 64 + m * 16 + g * 4;
#pragma unroll
    for (int n = 0; n < 4; ++n) {
      int col = col0 + wc * 64 + n * 16 + c;
      float bv = bias[col];
#pragma unroll
      for (int r = 0; r < 4; ++r) {
        float v = acc[m][n][r] + bv;
        C[(size_t)(row + r) * N + col] = (OutT)v;
      }
    }
  }
}

// ---------------- flash attention v4 --------------------------------------
// 1024 blocks, one q-tile (64 rows) each. 4 waves x 16 q-rows.
// 2-buffer KV pipeline (LDS 40KB -> 4 blocks/CU), one barrier + one
// counted-vmcnt wait per tile.
// Block mapping: idx = j + 256*slot, j = r*32 + bh. Under the dispatch
// model xcd=idx%8, cu=(idx/8)%32, slot=idx/256:
//  - idx%8 == bh%8: all 32 blocks of one (b,h) on one XCD (KV L2-local)
//  - per-CU slots get qt in {r, 31-r, r+8, 23-r}: work sum = 66 (uniform)
// Heuristic only; correctness never depends on dispatch (G16).
// mask: valid iff s <= q && !(s % 3 == 1 && s >= 4)
__global__ __launch_bounds__(256, 4) void k_attn(const bf16* __restrict__ qkv,
                                                 const bf16* __restrict__ vt,
                                                 bf16* __restrict__ att) {
  const int idx = blockIdx.x;
  const int slot = idx >> 8, j = idx & 255;
  const int r8 = j >> 5, bh = j & 31;
  const int b = bh >> 4, h = bh & 15;
  int qt;
  switch (slot) {
    case 0: qt = r8;       break;
    case 1: qt = 31 - r8;  break;
    case 2: qt = r8 + 8;   break;
    default: qt = 23 - r8; break;
  }

  const int tid = threadIdx.x;
  const int w = tid >> 6, l = tid & 63, g = l >> 4, c = l & 15;
  const int qw0 = qt * 64 + w * 16;
  const int nt = qt + 1;

  __shared__ bf16 Ks[2][64 * 64];    // [s][d] swizzled 128B rows (8KB each)
  __shared__ bf16 Vs[2][64 * 64];    // [d][s] swizzled 128B rows
  __shared__ bf16 Plds[4][16 * 64];  // per-wave [q][s] swizzled (2KB each)

  const bf16* kg = qkv + (size_t)(b * 2048) * 3072 + 1024 + h * 64;
  const bf16* vg = vt + (size_t)(b * 16 + h) * 64 * 2048;

  // stage KV tile t into buf (source pre-swizzled, dest linear)
  auto stage = [&](int buf, int t) {
    int s0 = t * 64;
#pragma unroll
    for (int it = 0; it < 2; ++it) {
      int ch = it * 256 + tid;
      int rr = ch >> 3, jj = (ch & 7) ^ (rr & 7);
      gload16(kg + (size_t)(s0 + rr) * 3072 + jj * 8, &Ks[buf][ch * 8]);
      gload16(vg + (size_t)rr * 2048 + s0 + jj * 8, &Vs[buf][ch * 8]);
    }
  };

  // Q A-frags, pre-scaled by 1/sqrt(64)=0.125 (exact in bf16)
  const bf16* qb = qkv + (size_t)(b * 2048 + qw0 + c) * 3072 + h * 64 + g * 8;
  bf16x8 qf0 = *(const bf16x8*)qb;
  bf16x8 qf1 = *(const bf16x8*)(qb + 32);
#pragma unroll
  for (int jq = 0; jq < 8; ++jq) {
    qf0[jq] = (bf16)((float)qf0[jq] * 0.125f);
    qf1[jq] = (bf16)((float)qf1[jq] * 0.125f);
  }

  f32x4 o[4] = {};
  float mrow[4] = {-1e30f, -1e30f, -1e30f, -1e30f};
  float ell[4] = {0.f, 0.f, 0.f, 0.f};

  stage(0, 0);

  int cur = 0;
#pragma unroll 1
  for (int t = 0; t < nt; ++t) {
    // only stage(t) is in flight: wait own share, then make visible to all
    asm volatile("s_waitcnt vmcnt(0)" ::: "memory");
    __builtin_amdgcn_sched_barrier(0);
    __builtin_amdgcn_s_barrier();       // all shares of stage(t) complete;
    __builtin_amdgcn_sched_barrier(0);  // all waves done reading tile t-1

    if (t + 1 < nt) stage(cur ^ 1, t + 1);  // overwrites t-1's buffer: safe

    // ---- S = Q K^T ----
    f32x4 ss[4] = {};
#pragma unroll
    for (int st = 0; st < 4; ++st) {
      bf16x8 ka  = *(const bf16x8*)swz(&Ks[cur][0], st * 16 + c, g * 16);
      bf16x8 kb2 = *(const bf16x8*)swz(&Ks[cur][0], st * 16 + c, 64 + g * 16);
      ss[st] = __builtin_amdgcn_mfma_f32_16x16x32_bf16(qf0, ka,  ss[st], 0, 0, 0);
      ss[st] = __builtin_amdgcn_mfma_f32_16x16x32_bf16(qf1, kb2, ss[st], 0, 0, 0);
    }

    // ---- mask (C-layout: row q = g*4+r, col s = t*64 + st*16 + c) ----
    const int sc = t * 64 + c;
    const bool diag = (t == qt);
    bool cm[4];
#pragma unroll
    for (int st = 0; st < 4; ++st) {
      int s = sc + st * 16;
      cm[st] = ((s % 3) == 1) && (s >= 4);
    }
    float mx[4];
#pragma unroll
    for (int r = 0; r < 4; ++r) {
      int q = qw0 + g * 4 + r;
      float m = -1e30f;
#pragma unroll
      for (int st = 0; st < 4; ++st) {
        int s = sc + st * 16;
        bool ok = !cm[st] && (!diag || s <= q);
        float v = ok ? ss[st][r] : -1e30f;
        ss[st][r] = v;
        m = fmaxf(m, v);
      }
      mx[r] = m;
    }
    // ---- online softmax (16-lane column groups) ----
#pragma unroll
    for (int r = 0; r < 4; ++r) {
      mx[r] = fmaxf(mx[r], __shfl_xor(mx[r], 1));
      mx[r] = fmaxf(mx[r], __shfl_xor(mx[r], 2));
      mx[r] = fmaxf(mx[r], __shfl_xor(mx[r], 4));
      mx[r] = fmaxf(mx[r], __shfl_xor(mx[r], 8));
    }
    float al[4];
#pragma unroll
    for (int r = 0; r < 4; ++r) {
      float mn = fmaxf(mrow[r], mx[r]);
      al[r] = __expf(mrow[r] - mn);
      mrow[r] = mn;
      float rsum = 0.f;
#pragma unroll
      for (int st = 0; st < 4; ++st) {
        float pv = __expf(ss[st][r] - mn);
        rsum += pv;
        *(bf16*)swz(&Plds[w][0], g * 4 + r, st * 32 + c * 2) = (bf16)pv;
      }
      rsum += __shfl_xor(rsum, 1);
      rsum += __shfl_xor(rsum, 2);
      rsum += __shfl_xor(rsum, 4);
      rsum += __shfl_xor(rsum, 8);
      ell[r] = ell[r] * al[r] + rsum;
    }
#pragma unroll
    for (int dc = 0; dc < 4; ++dc)
#pragma unroll
      for (int r = 0; r < 4; ++r) o[dc][r] *= al[r];

    // wave-private P round trip (rule #18 fence pair)
    asm volatile("s_waitcnt lgkmcnt(0)" ::: "memory");
    __builtin_amdgcn_sched_barrier(0);

    // ---- O += P @ V ----
#pragma unroll
    for (int kk = 0; kk < 2; ++kk) {
      bf16x8 pf = *(const bf16x8*)swz(&Plds[w][0], c, kk * 64 + g * 16);
#pragma unroll
      for (int dc = 0; dc < 4; ++dc) {
        bf16x8 vf = *(const bf16x8*)swz(&Vs[cur][0], dc * 16 + c, kk * 64 + g * 16);
        o[dc] = __builtin_amdgcn_mfma_f32_16x16x32_bf16(pf, vf, o[dc], 0, 0, 0);
      }
    }

    cur ^= 1;
  }

  // ---- epilogue ----
#pragma unroll
  for (int dc = 0; dc < 4; ++dc)
#pragma unroll
    for (int r = 0; r < 4; ++r) {
      int q = qw0 + g * 4 + r;
      att[(size_t)(b * 2048 + q) * 1024 + h * 64 + dc * 16 + c] =
          (bf16)(o[dc][r] / ell[r]);
    }
}

// ---------------- launcher ----------------
extern "C" void kernel_launch(void* const* d_in, const int* in_sizes, int n_in,
                              void* d_out, int out_size, void* d_ws, size_t ws_size,
                              hipStream_t stream) {
  const float* x  = (const float*)d_in[0];
  const float* Wq = (const float*)d_in[1];
  const float* bq = (const float*)d_in[2];
  const float* Wk = (const float*)d_in[3];
  const float* bk = (const float*)d_in[4];
  const float* Wv = (const float*)d_in[5];
  const float* bv = (const float*)d_in[6];
  const float* Wp = (const float*)d_in[7];
  const float* bp = (const float*)d_in[8];
  float* out = (float*)d_out;

  char* ws = (char*)d_ws;
  const size_t MB = 1024 * 1024;
  bf16*  xb    = (bf16*)(ws);             // 8 MB [4096][1024]; reused as att
  bf16*  wqkvT = (bf16*)(ws + 8 * MB);    // 6 MB [3072][1024]
  bf16*  wpT   = (bf16*)(ws + 14 * MB);   // 2 MB [1024][1024]
  float* bcat  = (float*)(ws + 16 * MB);  // 12 KB
  bf16*  qkv   = (bf16*)(ws + 17 * MB);   // 24 MB [4096][3072]
  bf16*  vtr   = (bf16*)(ws + 41 * MB);   // 8 MB [2][16][64][2048]
  bf16*  att   = xb;                      // alias: xb dead after QKV GEMM

  k_cvt_bf16<<<2048, 256, 0, stream>>>(x, xb, 524288);
  k_wt<<<512, 256, 0, stream>>>(Wq, wqkvT);
  k_wt<<<512, 256, 0, stream>>>(Wk, wqkvT + 1024 * 1024);
  k_wt<<<512, 256, 0, stream>>>(Wv, wqkvT + 2 * 1024 * 1024);
  k_wt<<<512, 256, 0, stream>>>(Wp, wpT);
  k_bcat<<<12, 256, 0, stream>>>(bq, bk, bv, bcat);

  k_gemm_bt<bf16><<<dim3(32, 24), 256, 0, stream>>>(xb, wqkvT, bcat, qkv, 1024, 3072);
  k_transpose_v<<<2048, 256, 0, stream>>>(qkv, vtr);
  k_attn<<<1024, 256, 0, stream>>>(qkv, vtr, att);
  k_gemm_bt<float><<<dim3(32, 8), 256, 0, stream>>>(att, wpT, bp, out, 1024, 1024);
}